// Round 19
// baseline (670.852 us; speedup 1.0000x reference)
//
#include <hip/hip_runtime.h>

#define NN_TOT 208896      // 32*96*68 nodes
#define E_TOT  1671168     // NN_TOT*8 edges
#define B_SZ   32
#define T_SZ   96
#define NPF    68          // nodes per frame
#define HID    128
#define NBINS  204         // 208896 / 1024 nodes per bin

typedef _Float16 f16x8 __attribute__((ext_vector_type(8)));
typedef _Float16 f16x2v __attribute__((ext_vector_type(2)));
typedef float f32x4 __attribute__((ext_vector_type(4)));

// ---------------- degree count ----------------
__global__ __launch_bounds__(256) void k_deg(const int* __restrict__ dst, int* __restrict__ cnt) {
    int e = blockIdx.x * 256 + threadIdx.x;
    atomicAdd(&cnt[dst[e]], 1);
}

// ---------------- scan part 1 (+ fused deg->norm) ----------------
__global__ __launch_bounds__(256) void k_scan1(const int* __restrict__ cnt, int* __restrict__ row_off,
                                               int* __restrict__ bsums, float* __restrict__ d_isqrt,
                                               float* __restrict__ self_norm) {
    __shared__ int ts[256];
    int tid = threadIdx.x;
    int base = blockIdx.x * 1024 + tid * 4;
    int v0 = cnt[base], v1 = cnt[base + 1], v2 = cnt[base + 2], v3 = cnt[base + 3];
#pragma unroll
    for (int u = 0; u < 4; ++u) {
        int vv = (u == 0) ? v0 : (u == 1) ? v1 : (u == 2) ? v2 : v3;
        float deg = (float)(1 + vv);
        float is = 1.0f / sqrtf(deg);
        d_isqrt[base + u] = is;
        self_norm[base + u] = is * is;
    }
    int s = v0 + v1 + v2 + v3;
    ts[tid] = s;
    __syncthreads();
    int inc = s;
    for (int off = 1; off < 256; off <<= 1) {
        int add = (tid >= off) ? ts[tid - off] : 0;
        __syncthreads();
        inc += add;
        ts[tid] = inc;
        __syncthreads();
    }
    int excl = inc - s;
    row_off[base] = excl;
    row_off[base + 1] = excl + v0;
    row_off[base + 2] = excl + v0 + v1;
    row_off[base + 3] = excl + v0 + v1 + v2;
    if (tid == 255) bsums[blockIdx.x] = inc;
}

__global__ __launch_bounds__(256) void k_scan2(int* __restrict__ bsums, int nb) {
    __shared__ int ts[256];
    int tid = threadIdx.x;
    int v = (tid < nb) ? bsums[tid] : 0;
    ts[tid] = v;
    __syncthreads();
    int inc = v;
    for (int off = 1; off < 256; off <<= 1) {
        int add = (tid >= off) ? ts[tid - off] : 0;
        __syncthreads();
        inc += add;
        ts[tid] = inc;
        __syncthreads();
    }
    if (tid < nb) bsums[tid] = inc - v;
}

// scan3 also seeds the per-bin append cursors (bin segment start = row_off at bin base)
__global__ __launch_bounds__(256) void k_scan3(int* __restrict__ row_off, const int* __restrict__ bsums,
                                               int* __restrict__ gcur) {
    int i = blockIdx.x * 256 + threadIdx.x;
    int v = row_off[i] + bsums[i >> 10];
    row_off[i] = v;
    if ((i & 1023) == 0) gcur[i >> 10] = v;
    if (i == 0) row_off[NN_TOT] = E_TOT;
}

// ---------------- CSR pass B: LDS-binned scatter into per-bin segments (dense bursts) ----------------
__global__ __launch_bounds__(256) void k_binscatter(const int* __restrict__ src, const int* __restrict__ dst,
                                                    int* __restrict__ gcur, int2* __restrict__ er_tmp) {
    __shared__ int hist[NBINS];
    __shared__ int lbase[NBINS];
    const int tid = threadIdx.x;
    for (int i = tid; i < NBINS; i += 256) hist[i] = 0;
    __syncthreads();
    const int be = blockIdx.x * 2048 + tid * 8;
    int s[8], d[8], rk[8];
    *(int4*)&s[0] = *(const int4*)&src[be];
    *(int4*)&s[4] = *(const int4*)&src[be + 4];
    *(int4*)&d[0] = *(const int4*)&dst[be];
    *(int4*)&d[4] = *(const int4*)&dst[be + 4];
#pragma unroll
    for (int j = 0; j < 8; ++j) rk[j] = atomicAdd(&hist[d[j] >> 10], 1);
    __syncthreads();
    for (int i = tid; i < NBINS; i += 256) lbase[i] = atomicAdd(&gcur[i], hist[i]);
    __syncthreads();
#pragma unroll
    for (int j = 0; j < 8; ++j) er_tmp[lbase[d[j] >> 10] + rk[j]] = make_int2(s[j], d[j]);
}

// ---------------- CSR pass C: within-bin sort to exact rows (64KB window, LDS cursors) + en ------
__global__ __launch_bounds__(256) void k_binsort(const int2* __restrict__ er_tmp, const int* __restrict__ row_off,
                                                 const float* __restrict__ d_isqrt, int2* __restrict__ er) {
    __shared__ int lcur[1024];
    __shared__ int lro[1024];
    __shared__ float lis[1024];
    const int tid = threadIdx.x;
    const int nb = blockIdx.x * 1024;
    for (int i = tid; i < 1024; i += 256) {
        lcur[i] = 0;
        lro[i] = row_off[nb + i];
        lis[i] = d_isqrt[nb + i];
    }
    __syncthreads();
    const int beg = row_off[nb];
    const int end = row_off[nb + 1024];  // blk 203: row_off[NN_TOT] = E_TOT
    for (int e = beg + tid; e < end; e += 256) {
        int2 ed = er_tmp[e];
        int loc = ed.y - nb;
        int p = atomicAdd(&lcur[loc], 1);
        float en = d_isqrt[ed.x] * lis[loc];
        er[lro[loc] + p] = make_int2(ed.x, __float_as_int(en));
    }
}

// ---------------- z0: 3-dim GCN0 aggregate (incl self) -> float4 (z0,z1,z2,self_norm) ----------------
__global__ __launch_bounds__(256) void k_z0(const float* __restrict__ x, const int* __restrict__ row_off,
                                            const int2* __restrict__ er, const float* __restrict__ self_norm,
                                            float4* __restrict__ z0out) {
    const int tid = threadIdx.x;
    const int blk = blockIdx.x;
    const int li = tid >> 2;         // local node 0..63
    const int slot = tid & 3;        // edge slot
    const int n = blk * 64 + li;
    const int beg = row_off[n], end = row_off[n + 1];
    float p0 = 0.f, p1 = 0.f, p2 = 0.f;
    for (int ei = beg + slot; ei < end; ei += 4) {
        int2 e = er[ei];
        float en = __int_as_float(e.y);
        const float* xs = x + 3 * (size_t)e.x;
        p0 = fmaf(xs[0], en, p0);
        p1 = fmaf(xs[1], en, p1);
        p2 = fmaf(xs[2], en, p2);
    }
    p0 += __shfl_xor(p0, 1); p1 += __shfl_xor(p1, 1); p2 += __shfl_xor(p2, 1);
    p0 += __shfl_xor(p0, 2); p1 += __shfl_xor(p1, 2); p2 += __shfl_xor(p2, 2);
    if (slot == 0) {
        const float sn = self_norm[n];
        const float* xn = x + 3 * (size_t)n;
        float4 z;
        z.x = fmaf(xn[0], sn, p0);
        z.y = fmaf(xn[1], sn, p1);
        z.z = fmaf(xn[2], sn, p2);
        z.w = sn;
        z0out[n] = z;
    }
}

// ---------------- fused: aggregation w/ packed-f16 h0 recompute + GEMM1 MFMA -> h1 ----------------
__global__ __launch_bounds__(256, 4) void k_agg_mm(const float4* __restrict__ z0, const int* __restrict__ row_off,
                                                   const int2* __restrict__ er, const _Float16* __restrict__ W0h,
                                                   const _Float16* __restrict__ b0h, const _Float16* __restrict__ W1p,
                                                   const float* __restrict__ b1, _Float16* __restrict__ h1) {
    __shared__ __align__(16) _Float16 As[64 * 136];  // rows padded to 136 f16 (272 B)
    const int tid = threadIdx.x;
    const int w = tid >> 6, lane = tid & 63;
    const int blk = blockIdx.x;

    // phase 1: per-lane edge loop, packed f16, all 32 cols in one pass
    {
        const int node = blk * 64 + lane;
        const int beg = row_off[node], end = row_off[node + 1];
        const f16x2v* __restrict__ W0p = (const f16x2v*)W0h;  // [3*64] pairs
        const f16x2v* __restrict__ b0p = (const f16x2v*)b0h;  // [64] pairs
        const int pb = w * 16;
        const f16x2v zero2 = {(_Float16)0.f, (_Float16)0.f};
        f16x2v w0p[16], w1p[16], w2p[16], bbp[16];
#pragma unroll
        for (int j = 0; j < 16; ++j) {
            w0p[j] = W0p[pb + j];
            w1p[j] = W0p[64 + pb + j];
            w2p[j] = W0p[128 + pb + j];
            bbp[j] = b0p[pb + j];
        }
        f16x2v accp[16];
        {  // self term (scaled by self_norm in zs.w)
            const float4 zs = z0[node];
            _Float16 sx = (_Float16)zs.x, sy = (_Float16)zs.y, sz = (_Float16)zs.z, sn = (_Float16)zs.w;
            f16x2v zxx = {sx, sx}, zyy = {sy, sy}, zzz = {sz, sz}, snn = {sn, sn};
#pragma unroll
            for (int j = 0; j < 16; ++j) {
                f16x2v t = zxx * w0p[j] + (zyy * w1p[j] + (zzz * w2p[j] + bbp[j]));
                t = __builtin_elementwise_max(t, zero2);
                accp[j] = t * snn;
            }
        }
        int ei = beg;
        for (; ei + 2 <= end; ei += 2) {
            int2 ea = er[ei], eb = er[ei + 1];
            float4 za = z0[ea.x];
            float4 zb = z0[eb.x];
            _Float16 ax = (_Float16)za.x, ay = (_Float16)za.y, az = (_Float16)za.z;
            _Float16 aen = (_Float16)__int_as_float(ea.y);
            _Float16 bx = (_Float16)zb.x, by = (_Float16)zb.y, bz = (_Float16)zb.z;
            _Float16 ben = (_Float16)__int_as_float(eb.y);
            f16x2v axx = {ax, ax}, ayy = {ay, ay}, azz = {az, az}, aee = {aen, aen};
            f16x2v bxx = {bx, bx}, byy = {by, by}, bzz = {bz, bz}, bee = {ben, ben};
#pragma unroll
            for (int j = 0; j < 16; ++j) {
                f16x2v t = axx * w0p[j] + (ayy * w1p[j] + (azz * w2p[j] + bbp[j]));
                t = __builtin_elementwise_max(t, zero2);
                accp[j] = t * aee + accp[j];
            }
#pragma unroll
            for (int j = 0; j < 16; ++j) {
                f16x2v t = bxx * w0p[j] + (byy * w1p[j] + (bzz * w2p[j] + bbp[j]));
                t = __builtin_elementwise_max(t, zero2);
                accp[j] = t * bee + accp[j];
            }
        }
        if (ei < end) {
            int2 e = er[ei];
            float4 za = z0[e.x];
            _Float16 ax = (_Float16)za.x, ay = (_Float16)za.y, az = (_Float16)za.z;
            _Float16 aen = (_Float16)__int_as_float(e.y);
            f16x2v axx = {ax, ax}, ayy = {ay, ay}, azz = {az, az}, aee = {aen, aen};
#pragma unroll
            for (int j = 0; j < 16; ++j) {
                f16x2v t = axx * w0p[j] + (ayy * w1p[j] + (azz * w2p[j] + bbp[j]));
                t = __builtin_elementwise_max(t, zero2);
                accp[j] = t * aee + accp[j];
            }
        }
        _Float16* dst = &As[lane * 136 + w * 32];
#pragma unroll
        for (int j = 0; j < 16; ++j) *(f16x2v*)(dst + 2 * j) = accp[j];
    }
    __syncthreads();

    // phase 2: MFMA 16x128x128; wave w owns m-tile rows w*16..w*16+15
    const int q = lane >> 4, c = lane & 15;
    f16x8 afr[4];
#pragma unroll
    for (int kk = 0; kk < 4; ++kk) afr[kk] = *(const f16x8*)(&As[(w * 16 + c) * 136 + kk * 32 + q * 8]);
    const f16x8* __restrict__ Bv = (const f16x8*)W1p;
    _Float16* Cst = &As[w * 2176];
#pragma unroll
    for (int j = 0; j < 8; ++j) {
        f32x4 cc = {0.f, 0.f, 0.f, 0.f};
#pragma unroll
        for (int kk = 0; kk < 4; ++kk)
            cc = __builtin_amdgcn_mfma_f32_16x16x32_f16(afr[kk], Bv[(j * 4 + kk) * 64 + lane], cc, 0, 0, 0);
        const float bi = b1[j * 16 + c];
#pragma unroll
        for (int r = 0; r < 4; ++r) Cst[(q * 4 + r) * 128 + j * 16 + c] = (_Float16)fmaxf(cc[r] + bi, 0.f);
    }
#pragma unroll
    for (int it = 0; it < 4; ++it) {
        int idx = it * 64 + lane;
        *(f16x8*)(h1 + (size_t)(blk * 64 + w * 16) * 128 + idx * 8) = *(const f16x8*)(&As[w * 2176 + idx * 8]);
    }
}

// ---------------- weight prep: WihT (f32) + f16 packs: W0h/b0h, W1p/Wmp frags, Whh frags ---------
__global__ __launch_bounds__(256) void k_prep(const float* __restrict__ Wih, const float* __restrict__ Whh,
                                              const float* __restrict__ W1, const float* __restrict__ Wm,
                                              const float* __restrict__ W0, const float* __restrict__ b0,
                                              float* __restrict__ WihT, _Float16* __restrict__ W1p,
                                              _Float16* __restrict__ Wmp, _Float16* __restrict__ Whhp,
                                              _Float16* __restrict__ W0h, _Float16* __restrict__ b0h) {
    int i = blockIdx.x * 256 + threadIdx.x;  // 0..49151
    {
        int o = i >> 7, k = i & 127;
        WihT[k * 384 + o] = Wih[i];
    }
    {
        // Whh frag pack: i = (f*64 + lane)*8 + e, f = (w*3+g)*4+kk
        int e = i & 7;
        int lane = (i >> 3) & 63;
        int f = i >> 9;  // 0..95
        int kk = f & 3, g = (f >> 2) % 3, wv = f / 12;
        int q = lane >> 4, c = lane & 15;
        Whhp[i] = (_Float16)Whh[(size_t)(g * 128 + 16 * wv + c) * 128 + kk * 32 + q * 8 + e];
    }
    if (i < 16384) {
        int f = i >> 9;          // frag id 0..31
        int j = f >> 2, kk = f & 3;
        int lane = (i >> 3) & 63;
        int e = i & 7;
        int q = lane >> 4, p = lane & 15;
        int k = kk * 32 + q * 8 + e, n = j * 16 + p;
        W1p[i] = (_Float16)W1[k * 128 + n];
        Wmp[i] = (_Float16)Wm[k * 128 + n];
    }
    if (i < 384) W0h[i] = (_Float16)W0[i];
    if (i < 128) b0h[i] = (_Float16)b0[i];
}

// ---------------- FUSED pool+GRU: producer-consumer overlap ----------------
// gru (4 blocks) was strictly serialized after mm_pool, idling 252 CUs for 84us. Now one launch:
// blocks 0..3 run the r15/r18 gru, blocks 4..1539 run mm_pool (2 frames/block, t-major dispatch so
// early timesteps finish first). Sync: producers __threadfence + release fetch_add(done_t[t],2);
// gru polls done_t (acquire, agent scope) once per 6-step chunk. Correct under any dispatch order;
// no deadlock (4 spinning blocks vs 252 free CUs).
union SMem {
    struct {
        __align__(16) _Float16 As[2][80 * 136];
        float colpart[2][512];
        float fr[2][128];
    } pool;
    struct {
        __align__(16) _Float16 hbuf[2][16 * 144];
    } gru;
};

#define GRU_BODY(PAR, GU, GL, JOFF)                                                                  \
    {                                                                                                \
        const _Float16* rb = hbuf[PAR];                                                              \
        _Float16* wb = hbuf[PAR ^ 1];                                                                \
        f16x8 afr[4];                                                                                \
        _Pragma("unroll") for (int kk = 0; kk < 4; ++kk)                                             \
            afr[kk] = *(const f16x8*)(&rb[c * 144 + kk * 32 + q * 8]);                               \
        const float* lp = pbp + (size_t)(JOFF + 2) * STRIDE;                                         \
        _Pragma("unroll") for (int r = 0; r < 4; ++r)                                                \
            _Pragma("unroll") for (int g = 0; g < 3; ++g)                                            \
                GL[r * 3 + g] = lp[r * 384 + g * 128];                                               \
        f32x4 cc[3];                                                                                 \
        _Pragma("unroll") for (int g = 0; g < 3; ++g) {                                              \
            f32x4 a = {0.f, 0.f, 0.f, 0.f};                                                          \
            _Pragma("unroll") for (int kk = 0; kk < 4; ++kk)                                         \
                a = __builtin_amdgcn_mfma_f32_16x16x32_f16(afr[kk], bfr[g][kk], a, 0, 0, 0);         \
            cc[g] = a;                                                                               \
        }                                                                                            \
        _Pragma("unroll") for (int r = 0; r < 4; ++r) {                                              \
            float hr = cc[0][r] + bh0, hz = cc[1][r] + bh1, hn = cc[2][r] + bh2;                     \
            float rg = __builtin_amdgcn_rcpf(1.f + exp2f(-LOG2E * (GU[r * 3 + 0] + hr)));            \
            float zg = __builtin_amdgcn_rcpf(1.f + exp2f(-LOG2E * (GU[r * 3 + 1] + hz)));            \
            float arg = GU[r * 3 + 2] + rg * hn;                                                     \
            float nn = 1.f - 2.f * __builtin_amdgcn_rcpf(exp2f(2.f * LOG2E * arg) + 1.f);            \
            h[r] = (1.f - zg) * nn + zg * h[r];                                                      \
            if (q < 2) wb[(q * 4 + r) * 144 + 16 * w + c] = (_Float16)h[r];                          \
        }                                                                                            \
        __syncthreads();                                                                             \
    }

__global__ __launch_bounds__(512) void k_pool_gru(const _Float16* __restrict__ h1, const _Float16* __restrict__ Wmp,
                                                  const float* __restrict__ bm, const float* __restrict__ WihT,
                                                  const float* __restrict__ bih, float* __restrict__ GIt,
                                                  const _Float16* __restrict__ Whhp, const float* __restrict__ bhh,
                                                  float* __restrict__ hT, int* __restrict__ done_t) {
    __shared__ SMem sm;
    const int tid = threadIdx.x;

    if (blockIdx.x >= 4) {
        // ---------------- producer: mm_pool, 2 frames per block, t-major ----------------
        const int blk = blockIdx.x - 4;   // 0..1535
        const int t = blk >> 4;           // timestep 0..95
        const int f = tid >> 8;           // frame half 0/1
        const int ftid = tid & 255;
        const int bb = (blk & 15) * 2 + f;  // batch 0..31
        const int w = ftid >> 6, lane = ftid & 63;
        const int q = lane >> 4, c = lane & 15;
        _Float16* As = sm.pool.As[f];
        float* colpart = sm.pool.colpart[f];
        float* fr = sm.pool.fr[f];
        const int bt = bb * T_SZ + t;

        const f16x8* __restrict__ srcv = (const f16x8*)(h1 + (size_t)bt * NPF * HID);
        for (int idx = ftid; idx < 80 * 17; idx += 256) {
            int row = idx / 17, ch = idx % 17;
            f16x8 v;
            if (row < NPF && ch < 16) {
                v = srcv[row * 16 + ch];
            } else {
#pragma unroll
                for (int k = 0; k < 8; ++k) v[k] = (_Float16)0.f;
            }
            *(f16x8*)(&As[row * 136 + ch * 8]) = v;
        }
        __syncthreads();

        const f16x8* __restrict__ Bv = (const f16x8*)Wmp;
        const int npass = (w == 0) ? 2 : 1;
        for (int pass = 0; pass < npass; ++pass) {
            const int mt = pass ? 4 : w;
            f16x8 afr[4];
#pragma unroll
            for (int kk = 0; kk < 4; ++kk) afr[kk] = *(const f16x8*)(&As[(mt * 16 + c) * 136 + kk * 32 + q * 8]);
#pragma unroll
            for (int j = 0; j < 8; ++j) {
                f32x4 cc = {0.f, 0.f, 0.f, 0.f};
#pragma unroll
                for (int kk = 0; kk < 4; ++kk)
                    cc = __builtin_amdgcn_mfma_f32_16x16x32_f16(afr[kk], Bv[(j * 4 + kk) * 64 + lane], cc, 0, 0, 0);
                const float bi = bm[j * 16 + c];
                float s = 0.f;
#pragma unroll
                for (int r = 0; r < 4; ++r) {
                    int m = mt * 16 + q * 4 + r;
                    float v = fmaxf(cc[r] + bi, 0.f);
                    s += (m < NPF) ? v : 0.f;
                }
                s += __shfl_xor(s, 16);
                s += __shfl_xor(s, 32);
                if (lane < 16) {
                    float* dst = &colpart[w * 128 + j * 16 + c];
                    *dst = (pass == 0) ? s : (*dst + s);
                }
            }
        }
        __syncthreads();
        if (ftid < 128)
            fr[ftid] = (colpart[ftid] + colpart[128 + ftid] + colpart[256 + ftid] + colpart[384 + ftid]) * (1.0f / NPF);
        __syncthreads();
        if (ftid < 128) {
#pragma unroll
            for (int p = 0; p < 3; ++p) {
                int o = ftid + p * 128;
                float a = bih[o];
#pragma unroll 8
                for (int k = 0; k < 128; ++k) a = fmaf(fr[k], WihT[k * 384 + o], a);
                GIt[((size_t)t * B_SZ + bb) * 384 + o] = a;  // time-major
            }
        }
        __threadfence();  // device-scope: all GIt stores visible before the flag
        __syncthreads();
        if (tid == 0) __hip_atomic_fetch_add(&done_t[t], 2, __ATOMIC_RELEASE, __HIP_MEMORY_SCOPE_AGENT);
        return;
    }

    // ---------------- consumer: gru (blocks 0..3, batches 8B..8B+7) ----------------
    _Float16(*hbuf)[16 * 144] = sm.gru.hbuf;
    const int w = tid >> 6, lane = tid & 63;
    const int q = lane >> 4, c = lane & 15;
    const int B = blockIdx.x;
    const float LOG2E = 1.44269504f;
    const int STRIDE = B_SZ * 384;

    f16x8 bfr[3][4];
#pragma unroll
    for (int g = 0; g < 3; ++g)
#pragma unroll
        for (int kk = 0; kk < 4; ++kk)
            bfr[g][kk] = *(const f16x8*)(Whhp + (size_t)(((w * 3 + g) * 4 + kk) * 64 + lane) * 8);
    const float bh0 = bhh[16 * w + c], bh1 = bhh[128 + 16 * w + c], bh2 = bhh[256 + 16 * w + c];
    for (int i = tid; i < 2 * 16 * 144 / 2; i += 512) ((unsigned int*)hbuf)[i] = 0u;  // BOTH buffers
    float h[4] = {0.f, 0.f, 0.f, 0.f};

    const int qq = (q < 2) ? q : 1;
    const float* pbp = GIt + (size_t)(B * 8 + qq * 4) * 384 + 16 * w + c;

    // wait for t=0,1 before priming the register pipeline
    if (tid == 0)
        while (__hip_atomic_load(&done_t[1], __ATOMIC_ACQUIRE, __HIP_MEMORY_SCOPE_AGENT) < 32)
            __builtin_amdgcn_s_sleep(16);
    __syncthreads();

    float g0[12], g1[12], g2[12];
#pragma unroll
    for (int r = 0; r < 4; ++r)
#pragma unroll
        for (int g = 0; g < 3; ++g) {
            g0[r * 3 + g] = pbp[r * 384 + g * 128];           // t = 0
            g1[r * 3 + g] = pbp[STRIDE + r * 384 + g * 128];  // t = 1
        }
    __syncthreads();

    for (int it = 0; it < T_SZ / 6; ++it) {
        const int tneed = (6 * it + 7 < T_SZ) ? 6 * it + 7 : T_SZ - 1;  // max t prefetched this chunk
        if (tid == 0)
            while (__hip_atomic_load(&done_t[tneed], __ATOMIC_ACQUIRE, __HIP_MEMORY_SCOPE_AGENT) < 32)
                __builtin_amdgcn_s_sleep(16);
        __syncthreads();
        GRU_BODY(0, g0, g2, 0)
        GRU_BODY(1, g1, g0, 1)
        GRU_BODY(0, g2, g1, 2)
        GRU_BODY(1, g0, g2, 3)
        GRU_BODY(0, g1, g0, 4)
        GRU_BODY(1, g2, g1, 5)
        pbp += 6 * (size_t)STRIDE;
    }
    if (q < 2) {
#pragma unroll
        for (int r = 0; r < 4; ++r) hT[(size_t)(B * 8 + q * 4 + r) * 128 + 16 * w + c] = h[r];
    }
}

// ---------------- classifier head (384 threads: phase 2 needs 320) ----------------
__global__ __launch_bounds__(384) void k_cls(const float* __restrict__ hT, const float* __restrict__ Wc1,
                                             const float* __restrict__ bc1, const float* __restrict__ Wc2,
                                             const float* __restrict__ bc2, float* __restrict__ out) {
    __shared__ float hid[32 * 64];
    int tid = threadIdx.x;
    for (int idx = tid; idx < 2048; idx += 384) {
        int b = idx >> 6, j = idx & 63;
        float a = bc1[j];
#pragma unroll 8
        for (int k = 0; k < 128; ++k) a = fmaf(hT[b * 128 + k], Wc1[k * 64 + j], a);
        hid[idx] = fmaxf(a, 0.f);
    }
    __syncthreads();
    if (tid < 320) {
        int b = tid / 10, c = tid % 10;
        float a = bc2[c];
#pragma unroll 8
        for (int k = 0; k < 64; ++k) a = fmaf(hid[b * 64 + k], Wc2[k * 10 + c], a);
        out[tid] = a;
    }
}

extern "C" void kernel_launch(void* const* d_in, const int* in_sizes, int n_in, void* d_out, int out_size, void* d_ws,
                              size_t ws_size, hipStream_t stream) {
    const float* x = (const float*)d_in[0];
    const int* ei = (const int*)d_in[1];
    const int* e_src = ei;
    const int* e_dst = ei + E_TOT;
    const float* W0 = (const float*)d_in[2];
    const float* b0 = (const float*)d_in[3];
    const float* W1 = (const float*)d_in[4];
    const float* b1 = (const float*)d_in[5];
    const float* Wm = (const float*)d_in[6];
    const float* bm = (const float*)d_in[7];
    const float* Wih = (const float*)d_in[8];
    const float* Whh = (const float*)d_in[9];
    const float* bih = (const float*)d_in[10];
    const float* bhh = (const float*)d_in[11];
    const float* Wc1 = (const float*)d_in[12];
    const float* bc1 = (const float*)d_in[13];
    const float* Wc2 = (const float*)d_in[14];
    const float* bc2 = (const float*)d_in[15];
    float* out = (float*)d_out;

    char* base = (char*)d_ws;
    size_t off = 0;
    auto alloc = [&](size_t bytes) {
        size_t o = off;
        off = (off + bytes + 255) & ~(size_t)255;
        return o;
    };
    size_t o_cnt = alloc((size_t)NN_TOT * 4);
    size_t o_rowoff = alloc((size_t)(NN_TOT + 1) * 4);
    size_t o_bsums = alloc(256 * 4);
    size_t o_gcur = alloc(256 * 4);
    size_t o_flags = alloc(256 * 4);  // done_t[96]
    size_t o_disqrt = alloc((size_t)NN_TOT * 4);
    size_t o_snorm = alloc((size_t)NN_TOT * 4);
    size_t o_er = alloc((size_t)E_TOT * 8);
    size_t o_ertmp = alloc((size_t)E_TOT * 8);
    size_t o_gi = alloc((size_t)(T_SZ + 2) * B_SZ * 384 * 4);  // +2 steps: branchless tail prefetch
    size_t o_wiht = alloc((size_t)128 * 384 * 4);
    size_t o_w1p = alloc((size_t)128 * 128 * 2);
    size_t o_wmp = alloc((size_t)128 * 128 * 2);
    size_t o_whhp = alloc((size_t)128 * 384 * 2);
    size_t o_w0h = alloc((size_t)384 * 2);
    size_t o_b0h = alloc((size_t)128 * 2);
    size_t o_ht = alloc((size_t)B_SZ * 128 * 4);
    size_t o_z0 = alloc((size_t)NN_TOT * 16);
    size_t o_h1 = alloc((size_t)NN_TOT * HID * 2);
    if (off > ws_size) return;  // workspace too small -> visible validation failure

    int* cnt = (int*)(base + o_cnt);
    int* row_off = (int*)(base + o_rowoff);
    int* bsums = (int*)(base + o_bsums);
    int* gcur = (int*)(base + o_gcur);
    int* done_t = (int*)(base + o_flags);
    float* d_isqrt = (float*)(base + o_disqrt);
    float* self_norm = (float*)(base + o_snorm);
    int2* er = (int2*)(base + o_er);
    int2* er_tmp = (int2*)(base + o_ertmp);
    float* GIt = (float*)(base + o_gi);
    float* WihT = (float*)(base + o_wiht);
    _Float16* W1p = (_Float16*)(base + o_w1p);
    _Float16* Wmp = (_Float16*)(base + o_wmp);
    _Float16* Whhp = (_Float16*)(base + o_whhp);
    _Float16* W0h = (_Float16*)(base + o_w0h);
    _Float16* b0h = (_Float16*)(base + o_b0h);
    float* hT = (float*)(base + o_ht);
    float4* z0 = (float4*)(base + o_z0);
    _Float16* h1 = (_Float16*)(base + o_h1);

    hipMemsetAsync(base + o_cnt, 0, (size_t)NN_TOT * 4, stream);  // cnt
    hipMemsetAsync(base + o_flags, 0, 256 * 4, stream);           // done_t

    k_deg<<<E_TOT / 256, 256, 0, stream>>>(e_dst, cnt);
    k_scan1<<<NN_TOT / 1024, 256, 0, stream>>>(cnt, row_off, bsums, d_isqrt, self_norm);
    k_scan2<<<1, 256, 0, stream>>>(bsums, NN_TOT / 1024);
    k_scan3<<<NN_TOT / 256, 256, 0, stream>>>(row_off, bsums, gcur);
    k_binscatter<<<E_TOT / 2048, 256, 0, stream>>>(e_src, e_dst, gcur, er_tmp);
    k_binsort<<<NBINS, 256, 0, stream>>>(er_tmp, row_off, d_isqrt, er);
    k_prep<<<(384 * 128) / 256, 256, 0, stream>>>(Wih, Whh, W1, Wm, W0, b0, WihT, W1p, Wmp, Whhp, W0h, b0h);
    k_z0<<<NN_TOT / 64, 256, 0, stream>>>(x, row_off, er, self_norm, z0);
    k_agg_mm<<<NN_TOT / 64, 256, 0, stream>>>(z0, row_off, er, W0h, b0h, W1p, b1, h1);
    k_pool_gru<<<4 + B_SZ * T_SZ / 2, 512, 0, stream>>>(h1, Wmp, bm, WihT, bih, GIt, Whhp, bhh, hT, done_t);
    k_cls<<<1, 384, 0, stream>>>(hT, Wc1, bc1, Wc2, bc2, out);
}

// Round 20
// 476.604 us; speedup vs baseline: 1.4076x; 1.4076x over previous
//
#include <hip/hip_runtime.h>

#define NN_TOT 208896      // 32*96*68 nodes
#define E_TOT  1671168     // NN_TOT*8 edges
#define B_SZ   32
#define T_SZ   96
#define NPF    68          // nodes per frame
#define HID    128
#define NBINS  204         // 208896 / 1024 nodes per bin

typedef _Float16 f16x8 __attribute__((ext_vector_type(8)));
typedef _Float16 f16x4v __attribute__((ext_vector_type(4)));
typedef _Float16 f16x2v __attribute__((ext_vector_type(2)));
typedef float f32x4 __attribute__((ext_vector_type(4)));

// ---------------- degree count ----------------
__global__ __launch_bounds__(256) void k_deg(const int* __restrict__ dst, int* __restrict__ cnt) {
    int e = blockIdx.x * 256 + threadIdx.x;
    atomicAdd(&cnt[dst[e]], 1);
}

// ---------------- scan part 1 (+ fused deg->norm) ----------------
__global__ __launch_bounds__(256) void k_scan1(const int* __restrict__ cnt, int* __restrict__ row_off,
                                               int* __restrict__ bsums, float* __restrict__ d_isqrt,
                                               float* __restrict__ self_norm) {
    __shared__ int ts[256];
    int tid = threadIdx.x;
    int base = blockIdx.x * 1024 + tid * 4;
    int v0 = cnt[base], v1 = cnt[base + 1], v2 = cnt[base + 2], v3 = cnt[base + 3];
#pragma unroll
    for (int u = 0; u < 4; ++u) {
        int vv = (u == 0) ? v0 : (u == 1) ? v1 : (u == 2) ? v2 : v3;
        float deg = (float)(1 + vv);
        float is = 1.0f / sqrtf(deg);
        d_isqrt[base + u] = is;
        self_norm[base + u] = is * is;
    }
    int s = v0 + v1 + v2 + v3;
    ts[tid] = s;
    __syncthreads();
    int inc = s;
    for (int off = 1; off < 256; off <<= 1) {
        int add = (tid >= off) ? ts[tid - off] : 0;
        __syncthreads();
        inc += add;
        ts[tid] = inc;
        __syncthreads();
    }
    int excl = inc - s;
    row_off[base] = excl;
    row_off[base + 1] = excl + v0;
    row_off[base + 2] = excl + v0 + v1;
    row_off[base + 3] = excl + v0 + v1 + v2;
    if (tid == 255) bsums[blockIdx.x] = inc;
}

__global__ __launch_bounds__(256) void k_scan2(int* __restrict__ bsums, int nb) {
    __shared__ int ts[256];
    int tid = threadIdx.x;
    int v = (tid < nb) ? bsums[tid] : 0;
    ts[tid] = v;
    __syncthreads();
    int inc = v;
    for (int off = 1; off < 256; off <<= 1) {
        int add = (tid >= off) ? ts[tid - off] : 0;
        __syncthreads();
        inc += add;
        ts[tid] = inc;
        __syncthreads();
    }
    if (tid < nb) bsums[tid] = inc - v;
}

// scan3 also seeds the per-bin append cursors (bin segment start = row_off at bin base)
__global__ __launch_bounds__(256) void k_scan3(int* __restrict__ row_off, const int* __restrict__ bsums,
                                               int* __restrict__ gcur) {
    int i = blockIdx.x * 256 + threadIdx.x;
    int v = row_off[i] + bsums[i >> 10];
    row_off[i] = v;
    if ((i & 1023) == 0) gcur[i >> 10] = v;
    if (i == 0) row_off[NN_TOT] = E_TOT;
}

// ---------------- CSR pass B: LDS-binned scatter into per-bin segments (dense bursts) ----------------
__global__ __launch_bounds__(256) void k_binscatter(const int* __restrict__ src, const int* __restrict__ dst,
                                                    int* __restrict__ gcur, int2* __restrict__ er_tmp) {
    __shared__ int hist[NBINS];
    __shared__ int lbase[NBINS];
    const int tid = threadIdx.x;
    for (int i = tid; i < NBINS; i += 256) hist[i] = 0;
    __syncthreads();
    const int be = blockIdx.x * 2048 + tid * 8;
    int s[8], d[8], rk[8];
    *(int4*)&s[0] = *(const int4*)&src[be];
    *(int4*)&s[4] = *(const int4*)&src[be + 4];
    *(int4*)&d[0] = *(const int4*)&dst[be];
    *(int4*)&d[4] = *(const int4*)&dst[be + 4];
#pragma unroll
    for (int j = 0; j < 8; ++j) rk[j] = atomicAdd(&hist[d[j] >> 10], 1);
    __syncthreads();
    for (int i = tid; i < NBINS; i += 256) lbase[i] = atomicAdd(&gcur[i], hist[i]);
    __syncthreads();
#pragma unroll
    for (int j = 0; j < 8; ++j) er_tmp[lbase[d[j] >> 10] + rk[j]] = make_int2(s[j], d[j]);
}

// ---------------- CSR pass C: within-bin sort to exact rows (64KB window, LDS cursors) + en ------
__global__ __launch_bounds__(256) void k_binsort(const int2* __restrict__ er_tmp, const int* __restrict__ row_off,
                                                 const float* __restrict__ d_isqrt, int2* __restrict__ er) {
    __shared__ int lcur[1024];
    __shared__ int lro[1024];
    __shared__ float lis[1024];
    const int tid = threadIdx.x;
    const int nb = blockIdx.x * 1024;
    for (int i = tid; i < 1024; i += 256) {
        lcur[i] = 0;
        lro[i] = row_off[nb + i];
        lis[i] = d_isqrt[nb + i];
    }
    __syncthreads();
    const int beg = row_off[nb];
    const int end = row_off[nb + 1024];  // blk 203: row_off[NN_TOT] = E_TOT
    for (int e = beg + tid; e < end; e += 256) {
        int2 ed = er_tmp[e];
        int loc = ed.y - nb;
        int p = atomicAdd(&lcur[loc], 1);
        float en = d_isqrt[ed.x] * lis[loc];
        er[lro[loc] + p] = make_int2(ed.x, __float_as_int(en));
    }
}

// ---------------- z0: 3-dim GCN0 aggregate (incl self) -> float4 (z0,z1,z2,self_norm) ----------------
__global__ __launch_bounds__(256) void k_z0(const float* __restrict__ x, const int* __restrict__ row_off,
                                            const int2* __restrict__ er, const float* __restrict__ self_norm,
                                            float4* __restrict__ z0out) {
    const int tid = threadIdx.x;
    const int blk = blockIdx.x;
    const int li = tid >> 2;         // local node 0..63
    const int slot = tid & 3;        // edge slot
    const int n = blk * 64 + li;
    const int beg = row_off[n], end = row_off[n + 1];
    float p0 = 0.f, p1 = 0.f, p2 = 0.f;
    for (int ei = beg + slot; ei < end; ei += 4) {
        int2 e = er[ei];
        float en = __int_as_float(e.y);
        const float* xs = x + 3 * (size_t)e.x;
        p0 = fmaf(xs[0], en, p0);
        p1 = fmaf(xs[1], en, p1);
        p2 = fmaf(xs[2], en, p2);
    }
    p0 += __shfl_xor(p0, 1); p1 += __shfl_xor(p1, 1); p2 += __shfl_xor(p2, 1);
    p0 += __shfl_xor(p0, 2); p1 += __shfl_xor(p1, 2); p2 += __shfl_xor(p2, 2);
    if (slot == 0) {
        const float sn = self_norm[n];
        const float* xn = x + 3 * (size_t)n;
        float4 z;
        z.x = fmaf(xn[0], sn, p0);
        z.y = fmaf(xn[1], sn, p1);
        z.z = fmaf(xn[2], sn, p2);
        z.w = sn;
        z0out[n] = z;
    }
}

// ---------------- fused: aggregation w/ packed-f16 h0 recompute + GEMM1 MFMA -> h1 ----------------
__global__ __launch_bounds__(256, 4) void k_agg_mm(const float4* __restrict__ z0, const int* __restrict__ row_off,
                                                   const int2* __restrict__ er, const _Float16* __restrict__ W0h,
                                                   const _Float16* __restrict__ b0h, const _Float16* __restrict__ W1p,
                                                   const float* __restrict__ b1, _Float16* __restrict__ h1) {
    __shared__ __align__(16) _Float16 As[64 * 136];  // rows padded to 136 f16 (272 B)
    const int tid = threadIdx.x;
    const int w = tid >> 6, lane = tid & 63;
    const int blk = blockIdx.x;

    // phase 1: per-lane edge loop, packed f16, all 32 cols in one pass
    {
        const int node = blk * 64 + lane;
        const int beg = row_off[node], end = row_off[node + 1];
        const f16x2v* __restrict__ W0p = (const f16x2v*)W0h;  // [3*64] pairs
        const f16x2v* __restrict__ b0p = (const f16x2v*)b0h;  // [64] pairs
        const int pb = w * 16;
        const f16x2v zero2 = {(_Float16)0.f, (_Float16)0.f};
        f16x2v w0p[16], w1p[16], w2p[16], bbp[16];
#pragma unroll
        for (int j = 0; j < 16; ++j) {
            w0p[j] = W0p[pb + j];
            w1p[j] = W0p[64 + pb + j];
            w2p[j] = W0p[128 + pb + j];
            bbp[j] = b0p[pb + j];
        }
        f16x2v accp[16];
        {  // self term (scaled by self_norm in zs.w)
            const float4 zs = z0[node];
            _Float16 sx = (_Float16)zs.x, sy = (_Float16)zs.y, sz = (_Float16)zs.z, sn = (_Float16)zs.w;
            f16x2v zxx = {sx, sx}, zyy = {sy, sy}, zzz = {sz, sz}, snn = {sn, sn};
#pragma unroll
            for (int j = 0; j < 16; ++j) {
                f16x2v t = zxx * w0p[j] + (zyy * w1p[j] + (zzz * w2p[j] + bbp[j]));
                t = __builtin_elementwise_max(t, zero2);
                accp[j] = t * snn;
            }
        }
        int ei = beg;
        for (; ei + 2 <= end; ei += 2) {
            int2 ea = er[ei], eb = er[ei + 1];
            float4 za = z0[ea.x];
            float4 zb = z0[eb.x];
            _Float16 ax = (_Float16)za.x, ay = (_Float16)za.y, az = (_Float16)za.z;
            _Float16 aen = (_Float16)__int_as_float(ea.y);
            _Float16 bx = (_Float16)zb.x, by = (_Float16)zb.y, bz = (_Float16)zb.z;
            _Float16 ben = (_Float16)__int_as_float(eb.y);
            f16x2v axx = {ax, ax}, ayy = {ay, ay}, azz = {az, az}, aee = {aen, aen};
            f16x2v bxx = {bx, bx}, byy = {by, by}, bzz = {bz, bz}, bee = {ben, ben};
#pragma unroll
            for (int j = 0; j < 16; ++j) {
                f16x2v t = axx * w0p[j] + (ayy * w1p[j] + (azz * w2p[j] + bbp[j]));
                t = __builtin_elementwise_max(t, zero2);
                accp[j] = t * aee + accp[j];
            }
#pragma unroll
            for (int j = 0; j < 16; ++j) {
                f16x2v t = bxx * w0p[j] + (byy * w1p[j] + (bzz * w2p[j] + bbp[j]));
                t = __builtin_elementwise_max(t, zero2);
                accp[j] = t * bee + accp[j];
            }
        }
        if (ei < end) {
            int2 e = er[ei];
            float4 za = z0[e.x];
            _Float16 ax = (_Float16)za.x, ay = (_Float16)za.y, az = (_Float16)za.z;
            _Float16 aen = (_Float16)__int_as_float(e.y);
            f16x2v axx = {ax, ax}, ayy = {ay, ay}, azz = {az, az}, aee = {aen, aen};
#pragma unroll
            for (int j = 0; j < 16; ++j) {
                f16x2v t = axx * w0p[j] + (ayy * w1p[j] + (azz * w2p[j] + bbp[j]));
                t = __builtin_elementwise_max(t, zero2);
                accp[j] = t * aee + accp[j];
            }
        }
        _Float16* dst = &As[lane * 136 + w * 32];
#pragma unroll
        for (int j = 0; j < 16; ++j) *(f16x2v*)(dst + 2 * j) = accp[j];
    }
    __syncthreads();

    // phase 2: MFMA 16x128x128; wave w owns m-tile rows w*16..w*16+15
    const int q = lane >> 4, c = lane & 15;
    f16x8 afr[4];
#pragma unroll
    for (int kk = 0; kk < 4; ++kk) afr[kk] = *(const f16x8*)(&As[(w * 16 + c) * 136 + kk * 32 + q * 8]);
    const f16x8* __restrict__ Bv = (const f16x8*)W1p;
    _Float16* Cst = &As[w * 2176];
#pragma unroll
    for (int j = 0; j < 8; ++j) {
        f32x4 cc = {0.f, 0.f, 0.f, 0.f};
#pragma unroll
        for (int kk = 0; kk < 4; ++kk)
            cc = __builtin_amdgcn_mfma_f32_16x16x32_f16(afr[kk], Bv[(j * 4 + kk) * 64 + lane], cc, 0, 0, 0);
        const float bi = b1[j * 16 + c];
#pragma unroll
        for (int r = 0; r < 4; ++r) Cst[(q * 4 + r) * 128 + j * 16 + c] = (_Float16)fmaxf(cc[r] + bi, 0.f);
    }
#pragma unroll
    for (int it = 0; it < 4; ++it) {
        int idx = it * 64 + lane;
        *(f16x8*)(h1 + (size_t)(blk * 64 + w * 16) * 128 + idx * 8) = *(const f16x8*)(&As[w * 2176 + idx * 8]);
    }
}

// ---------------- weight prep: WihT (f32) + f16 packs: W0h/b0h, W1p/Wmp frags, Whh frags ---------
__global__ __launch_bounds__(256) void k_prep(const float* __restrict__ Wih, const float* __restrict__ Whh,
                                              const float* __restrict__ W1, const float* __restrict__ Wm,
                                              const float* __restrict__ W0, const float* __restrict__ b0,
                                              float* __restrict__ WihT, _Float16* __restrict__ W1p,
                                              _Float16* __restrict__ Wmp, _Float16* __restrict__ Whhp,
                                              _Float16* __restrict__ W0h, _Float16* __restrict__ b0h) {
    int i = blockIdx.x * 256 + threadIdx.x;  // 0..49151
    {
        int o = i >> 7, k = i & 127;
        WihT[k * 384 + o] = Wih[i];
    }
    {
        // Whh frag pack: i = (f*64 + lane)*8 + e, f = (w*3+g)*4+kk
        int e = i & 7;
        int lane = (i >> 3) & 63;
        int f = i >> 9;  // 0..95
        int kk = f & 3, g = (f >> 2) % 3, wv = f / 12;
        int q = lane >> 4, c = lane & 15;
        Whhp[i] = (_Float16)Whh[(size_t)(g * 128 + 16 * wv + c) * 128 + kk * 32 + q * 8 + e];
    }
    if (i < 16384) {
        int f = i >> 9;          // frag id 0..31
        int j = f >> 2, kk = f & 3;
        int lane = (i >> 3) & 63;
        int e = i & 7;
        int q = lane >> 4, p = lane & 15;
        int k = kk * 32 + q * 8 + e, n = j * 16 + p;
        W1p[i] = (_Float16)W1[k * 128 + n];
        Wmp[i] = (_Float16)Wm[k * 128 + n];
    }
    if (i < 384) W0h[i] = (_Float16)W0[i];
    if (i < 128) b0h[i] = (_Float16)b0[i];
}

// ---------------- fused: GEMM2 (f16 MFMA) + relu + frame mean + gi precompute (time-major out) ----
__global__ __launch_bounds__(256) void k_mm_pool(const _Float16* __restrict__ h1, const _Float16* __restrict__ Wmp,
                                                 const float* __restrict__ bm, const float* __restrict__ WihT,
                                                 const float* __restrict__ bih, float* __restrict__ GIt) {
    __shared__ __align__(16) _Float16 As[80 * 136];
    __shared__ float colpart[4 * 128];
    __shared__ float fr[128];
    const int tid = threadIdx.x;
    const int w = tid >> 6, lane = tid & 63;
    const int q = lane >> 4, c = lane & 15;
    const int bt = blockIdx.x;
    const int bb = bt / T_SZ, tt = bt % T_SZ;

    const f16x8* __restrict__ srcv = (const f16x8*)(h1 + (size_t)bt * NPF * HID);
    for (int idx = tid; idx < 80 * 17; idx += 256) {
        int row = idx / 17, ch = idx % 17;
        f16x8 v;
        if (row < NPF && ch < 16) {
            v = srcv[row * 16 + ch];
        } else {
#pragma unroll
            for (int k = 0; k < 8; ++k) v[k] = (_Float16)0.f;
        }
        *(f16x8*)(&As[row * 136 + ch * 8]) = v;
    }
    __syncthreads();

    const f16x8* __restrict__ Bv = (const f16x8*)Wmp;
    const int npass = (w == 0) ? 2 : 1;
    for (int pass = 0; pass < npass; ++pass) {
        const int mt = pass ? 4 : w;
        f16x8 afr[4];
#pragma unroll
        for (int kk = 0; kk < 4; ++kk) afr[kk] = *(const f16x8*)(&As[(mt * 16 + c) * 136 + kk * 32 + q * 8]);
#pragma unroll
        for (int j = 0; j < 8; ++j) {
            f32x4 cc = {0.f, 0.f, 0.f, 0.f};
#pragma unroll
            for (int kk = 0; kk < 4; ++kk)
                cc = __builtin_amdgcn_mfma_f32_16x16x32_f16(afr[kk], Bv[(j * 4 + kk) * 64 + lane], cc, 0, 0, 0);
            const float bi = bm[j * 16 + c];
            float s = 0.f;
#pragma unroll
            for (int r = 0; r < 4; ++r) {
                int m = mt * 16 + q * 4 + r;
                float v = fmaxf(cc[r] + bi, 0.f);
                s += (m < NPF) ? v : 0.f;
            }
            s += __shfl_xor(s, 16);
            s += __shfl_xor(s, 32);
            if (lane < 16) {
                float* dst = &colpart[w * 128 + j * 16 + c];
                *dst = (pass == 0) ? s : (*dst + s);
            }
        }
    }
    __syncthreads();
    if (tid < 128)
        fr[tid] = (colpart[tid] + colpart[128 + tid] + colpart[256 + tid] + colpart[384 + tid]) * (1.0f / NPF);
    __syncthreads();
    if (tid < 128) {
#pragma unroll
        for (int p = 0; p < 3; ++p) {
            int o = tid + p * 128;
            float a = bih[o];
#pragma unroll 8
            for (int k = 0; k < 128; ++k) a = fmaf(fr[k], WihT[k * 384 + o], a);
            GIt[((size_t)tt * B_SZ + bb) * 384 + o] = a;  // time-major for the GRU
        }
    }
}

// ---------------- GRU recurrence: batch-split 4 blocks x 8 batches (best measured variant) ------
#define GRU_BODY(PAR, GU, GL, JOFF)                                                                  \
    {                                                                                                \
        const _Float16* rb = hbuf[PAR];                                                              \
        _Float16* wb = hbuf[PAR ^ 1];                                                                \
        f16x8 afr[4];                                                                                \
        _Pragma("unroll") for (int kk = 0; kk < 4; ++kk)                                             \
            afr[kk] = *(const f16x8*)(&rb[c * 144 + kk * 32 + q * 8]);                               \
        const float* lp = pb + (size_t)(JOFF + 2) * STRIDE;                                          \
        _Pragma("unroll") for (int r = 0; r < 4; ++r)                                                \
            _Pragma("unroll") for (int g = 0; g < 3; ++g)                                            \
                GL[r * 3 + g] = lp[r * 384 + g * 128];                                               \
        f32x4 cc[3];                                                                                 \
        _Pragma("unroll") for (int g = 0; g < 3; ++g) {                                              \
            f32x4 a = {0.f, 0.f, 0.f, 0.f};                                                          \
            _Pragma("unroll") for (int kk = 0; kk < 4; ++kk)                                         \
                a = __builtin_amdgcn_mfma_f32_16x16x32_f16(afr[kk], bfr[g][kk], a, 0, 0, 0);         \
            cc[g] = a;                                                                               \
        }                                                                                            \
        _Pragma("unroll") for (int r = 0; r < 4; ++r) {                                              \
            float hr = cc[0][r] + bh0, hz = cc[1][r] + bh1, hn = cc[2][r] + bh2;                     \
            float rg = __builtin_amdgcn_rcpf(1.f + exp2f(-LOG2E * (GU[r * 3 + 0] + hr)));            \
            float zg = __builtin_amdgcn_rcpf(1.f + exp2f(-LOG2E * (GU[r * 3 + 1] + hz)));            \
            float arg = GU[r * 3 + 2] + rg * hn;                                                     \
            float nn = 1.f - 2.f * __builtin_amdgcn_rcpf(exp2f(2.f * LOG2E * arg) + 1.f);            \
            h[r] = (1.f - zg) * nn + zg * h[r];                                                      \
            if (q < 2) wb[(q * 4 + r) * 144 + 16 * w + c] = (_Float16)h[r];                          \
        }                                                                                            \
        __syncthreads();                                                                             \
    }

__global__ __launch_bounds__(512) __attribute__((amdgpu_waves_per_eu(1, 2)))
void k_gru(const float* __restrict__ GIt, const _Float16* __restrict__ Whhp,
           const float* __restrict__ bhh, float* __restrict__ hT) {
    __shared__ __align__(16) _Float16 hbuf[2][16 * 144];
    const int tid = threadIdx.x;
    const int w = tid >> 6, lane = tid & 63;
    const int q = lane >> 4, c = lane & 15;
    const int B = blockIdx.x;  // batches 8B..8B+7
    const float LOG2E = 1.44269504f;
    const int STRIDE = B_SZ * 384;

    f16x8 bfr[3][4];
#pragma unroll
    for (int g = 0; g < 3; ++g)
#pragma unroll
        for (int kk = 0; kk < 4; ++kk)
            bfr[g][kk] = *(const f16x8*)(Whhp + (size_t)(((w * 3 + g) * 4 + kk) * 64 + lane) * 8);
    const float bh0 = bhh[16 * w + c], bh1 = bhh[128 + 16 * w + c], bh2 = bhh[256 + 16 * w + c];
    for (int i = tid; i < 2 * 16 * 144 / 2; i += 512) ((unsigned int*)hbuf)[i] = 0u;  // BOTH buffers
    float h[4] = {0.f, 0.f, 0.f, 0.f};

    const int qq = (q < 2) ? q : 1;  // lanes for rows 8-15 duplicate rows 4-7's addresses
    const float* pb = GIt + (size_t)(B * 8 + qq * 4) * 384 + 16 * w + c;
    float g0[12], g1[12], g2[12];
#pragma unroll
    for (int r = 0; r < 4; ++r)
#pragma unroll
        for (int g = 0; g < 3; ++g) {
            g0[r * 3 + g] = pb[r * 384 + g * 128];           // t = 0
            g1[r * 3 + g] = pb[STRIDE + r * 384 + g * 128];  // t = 1
        }
    __syncthreads();

    for (int it = 0; it < T_SZ / 6; ++it) {
        GRU_BODY(0, g0, g2, 0)
        GRU_BODY(1, g1, g0, 1)
        GRU_BODY(0, g2, g1, 2)
        GRU_BODY(1, g0, g2, 3)
        GRU_BODY(0, g1, g0, 4)
        GRU_BODY(1, g2, g1, 5)
        pb += 6 * (size_t)STRIDE;
    }
    if (q < 2) {
#pragma unroll
        for (int r = 0; r < 4; ++r) hT[(size_t)(B * 8 + q * 4 + r) * 128 + 16 * w + c] = h[r];
    }
}

// ---------------- classifier head (384 threads: phase 2 needs 320) ----------------
__global__ __launch_bounds__(384) void k_cls(const float* __restrict__ hT, const float* __restrict__ Wc1,
                                             const float* __restrict__ bc1, const float* __restrict__ Wc2,
                                             const float* __restrict__ bc2, float* __restrict__ out) {
    __shared__ float hid[32 * 64];
    int tid = threadIdx.x;
    for (int idx = tid; idx < 2048; idx += 384) {
        int b = idx >> 6, j = idx & 63;
        float a = bc1[j];
#pragma unroll 8
        for (int k = 0; k < 128; ++k) a = fmaf(hT[b * 128 + k], Wc1[k * 64 + j], a);
        hid[idx] = fmaxf(a, 0.f);
    }
    __syncthreads();
    if (tid < 320) {
        int b = tid / 10, c = tid % 10;
        float a = bc2[c];
#pragma unroll 8
        for (int k = 0; k < 64; ++k) a = fmaf(hid[b * 64 + k], Wc2[k * 10 + c], a);
        out[tid] = a;
    }
}

extern "C" void kernel_launch(void* const* d_in, const int* in_sizes, int n_in, void* d_out, int out_size, void* d_ws,
                              size_t ws_size, hipStream_t stream) {
    const float* x = (const float*)d_in[0];
    const int* ei = (const int*)d_in[1];
    const int* e_src = ei;
    const int* e_dst = ei + E_TOT;
    const float* W0 = (const float*)d_in[2];
    const float* b0 = (const float*)d_in[3];
    const float* W1 = (const float*)d_in[4];
    const float* b1 = (const float*)d_in[5];
    const float* Wm = (const float*)d_in[6];
    const float* bm = (const float*)d_in[7];
    const float* Wih = (const float*)d_in[8];
    const float* Whh = (const float*)d_in[9];
    const float* bih = (const float*)d_in[10];
    const float* bhh = (const float*)d_in[11];
    const float* Wc1 = (const float*)d_in[12];
    const float* bc1 = (const float*)d_in[13];
    const float* Wc2 = (const float*)d_in[14];
    const float* bc2 = (const float*)d_in[15];
    float* out = (float*)d_out;

    char* base = (char*)d_ws;
    size_t off = 0;
    auto alloc = [&](size_t bytes) {
        size_t o = off;
        off = (off + bytes + 255) & ~(size_t)255;
        return o;
    };
    size_t o_cnt = alloc((size_t)NN_TOT * 4);
    size_t o_rowoff = alloc((size_t)(NN_TOT + 1) * 4);
    size_t o_bsums = alloc(256 * 4);
    size_t o_gcur = alloc(256 * 4);
    size_t o_disqrt = alloc((size_t)NN_TOT * 4);
    size_t o_snorm = alloc((size_t)NN_TOT * 4);
    size_t o_er = alloc((size_t)E_TOT * 8);
    size_t o_ertmp = alloc((size_t)E_TOT * 8);
    size_t o_gi = alloc((size_t)(T_SZ + 2) * B_SZ * 384 * 4);  // +2 steps: branchless tail prefetch
    size_t o_wiht = alloc((size_t)128 * 384 * 4);
    size_t o_w1p = alloc((size_t)128 * 128 * 2);
    size_t o_wmp = alloc((size_t)128 * 128 * 2);
    size_t o_whhp = alloc((size_t)128 * 384 * 2);
    size_t o_w0h = alloc((size_t)384 * 2);
    size_t o_b0h = alloc((size_t)128 * 2);
    size_t o_ht = alloc((size_t)B_SZ * 128 * 4);
    size_t o_z0 = alloc((size_t)NN_TOT * 16);
    size_t o_h1 = alloc((size_t)NN_TOT * HID * 2);
    if (off > ws_size) return;  // workspace too small -> visible validation failure

    int* cnt = (int*)(base + o_cnt);
    int* row_off = (int*)(base + o_rowoff);
    int* bsums = (int*)(base + o_bsums);
    int* gcur = (int*)(base + o_gcur);
    float* d_isqrt = (float*)(base + o_disqrt);
    float* self_norm = (float*)(base + o_snorm);
    int2* er = (int2*)(base + o_er);
    int2* er_tmp = (int2*)(base + o_ertmp);
    float* GIt = (float*)(base + o_gi);
    float* WihT = (float*)(base + o_wiht);
    _Float16* W1p = (_Float16*)(base + o_w1p);
    _Float16* Wmp = (_Float16*)(base + o_wmp);
    _Float16* Whhp = (_Float16*)(base + o_whhp);
    _Float16* W0h = (_Float16*)(base + o_w0h);
    _Float16* b0h = (_Float16*)(base + o_b0h);
    float* hT = (float*)(base + o_ht);
    float4* z0 = (float4*)(base + o_z0);
    _Float16* h1 = (_Float16*)(base + o_h1);

    hipMemsetAsync(base + o_cnt, 0, (size_t)NN_TOT * 4, stream);  // cnt only

    k_deg<<<E_TOT / 256, 256, 0, stream>>>(e_dst, cnt);
    k_scan1<<<NN_TOT / 1024, 256, 0, stream>>>(cnt, row_off, bsums, d_isqrt, self_norm);
    k_scan2<<<1, 256, 0, stream>>>(bsums, NN_TOT / 1024);
    k_scan3<<<NN_TOT / 256, 256, 0, stream>>>(row_off, bsums, gcur);
    k_binscatter<<<E_TOT / 2048, 256, 0, stream>>>(e_src, e_dst, gcur, er_tmp);
    k_binsort<<<NBINS, 256, 0, stream>>>(er_tmp, row_off, d_isqrt, er);
    k_prep<<<(384 * 128) / 256, 256, 0, stream>>>(Wih, Whh, W1, Wm, W0, b0, WihT, W1p, Wmp, Whhp, W0h, b0h);
    k_z0<<<NN_TOT / 64, 256, 0, stream>>>(x, row_off, er, self_norm, z0);
    k_agg_mm<<<NN_TOT / 64, 256, 0, stream>>>(z0, row_off, er, W0h, b0h, W1p, b1, h1);
    k_mm_pool<<<B_SZ * T_SZ, 256, 0, stream>>>(h1, Wmp, bm, WihT, bih, GIt);
    k_gru<<<4, 512, 0, stream>>>(GIt, Whhp, bhh, hT);
    k_cls<<<1, 384, 0, stream>>>(hT, Wc1, bc1, Wc2, bc2, out);
}